// Round 13
// baseline (224.879 us; speedup 1.0000x reference)
//
#include <hip/hip_runtime.h>
#include <hip/hip_bf16.h>
#include <math.h>

#define BB 64
#define TT 500
#define DD 64
#define SS 50
#define PP 10            // chunks
#define LL 50            // steps per chunk (PP*LL == TT)

typedef float v2f __attribute__((ext_vector_type(2)));

__device__ __forceinline__ float sigmoidf_(float x) { return 1.0f / (1.0f + __expf(-x)); }

// ---------------------------------------------------------------------------
// Kernel 1: tables. blocks [0,ncon): wTab[c][50] = softmax(embed_key[c]·Mk^T)
//   blocks [ncon,ncon+nv): eaTab[x][d] = {sigmoid(ev@We+be), tanh(ev@Wa+ba)}
// ---------------------------------------------------------------------------
__global__ __launch_bounds__(64) void k1_tables(
    const float* __restrict__ embed_key,
    const float* __restrict__ embed_value,
    const float* __restrict__ Mk,
    const float* __restrict__ We, const float* __restrict__ be,
    const float* __restrict__ Wa, const float* __restrict__ ba,
    int ncon, int nv,
    float* __restrict__ wTab, float* __restrict__ eaTab)
{
    const int lane = threadIdx.x;
    if ((int)blockIdx.x < ncon) {
        const int c = blockIdx.x;
        __shared__ float mkS[SS][DD + 1];
        __shared__ float kS[DD];
        kS[lane] = embed_key[c * DD + lane];
        for (int s = 0; s < SS; ++s)
            mkS[s][lane] = Mk[s * DD + lane];
        __syncthreads();

        float sc = -1e30f;
        if (lane < SS) {
            float acc = 0.f;
            #pragma unroll
            for (int dd = 0; dd < DD; ++dd)
                acc = fmaf(kS[dd], mkS[lane][dd], acc);
            sc = acc;
        }
        float m = sc;
        #pragma unroll
        for (int off = 32; off >= 1; off >>= 1)
            m = fmaxf(m, __shfl_xor(m, off));
        float ex = (lane < SS) ? __expf(sc - m) : 0.f;
        float ssum = ex;
        #pragma unroll
        for (int off = 32; off >= 1; off >>= 1)
            ssum += __shfl_xor(ssum, off);
        if (lane < SS)
            wTab[c * SS + lane] = ex / ssum;
    } else {
        const int x = blockIdx.x - ncon;
        __shared__ float vS[DD];
        vS[lane] = embed_value[x * DD + lane];
        __syncthreads();
        float acc_e = be[lane];
        float acc_a = ba[lane];
        #pragma unroll
        for (int i = 0; i < DD; ++i) {
            const float vi = vS[i];
            acc_e = fmaf(vi, We[i * DD + lane], acc_e);
            acc_a = fmaf(vi, Wa[i * DD + lane], acc_a);
        }
        float2 ea;
        ea.x = sigmoidf_(acc_e);
        ea.y = tanhf(acc_a);
        *(float2*)&eaTab[((size_t)x * DD + lane) * 2] = ea;
    }
}

// ---------------------------------------------------------------------------
// PARALLEL SCAN over t (round 12 win). Recurrence per (b,s,d): m <- al*m + be
// with al = 1-w*e, be = w*a. Chunk maps compose associatively.
//   k2a:     per (b,p) compose the 50-step chunk map (A,B)
//   k2fused: per (b,p) prefix-compose start state in regs (k2b folded in),
//            replay 50 steps computing r into LDS, then the OUTPUT HEAD
//            in-block (k3 folded in) -> writes out[] directly.
// ---------------------------------------------------------------------------

#define SCAN_STAGE()                                                          \
    const int b = blockIdx.x / PP, p = blockIdx.x % PP;                       \
    const int tid = threadIdx.x;                                              \
    const int lane = tid & 63, sg = tid >> 6;                                 \
    const int t0g = p * LL;                                                   \
    if (tid < LL) {                                                           \
        const int c = cseq[b * TT + t0g + tid];                               \
        cL[tid] = c;                                                          \
        xL[tid] = c + ncp[0] * corr[b * TT + t0g + tid];                      \
    }                                                                         \
    __syncthreads();                                                          \
    for (int i = tid; i < LL * 64; i += 256) {                                \
        const int t = i >> 6, l = i & 63;                                     \
        const int sg_ = l >> 4, j_ = l & 15;                                  \
        const int st_ = (SS * sg_) >> 2, en_ = (SS * (sg_ + 1)) >> 2;         \
        const int s_ = st_ + j_;                                              \
        wLds[t][l] = (s_ < en_) ? wTab[cL[t] * SS + s_] : 0.f;                \
        eaLds[t][l] = *(const float2*)&eaTab[((size_t)xL[t] * DD + l) * 2];   \
    }

#define LOADW(t)                                                              \
    const float4 wv0 = *(const float4*)&wLds[t][sg * 16];                     \
    const float4 wv1 = *(const float4*)&wLds[t][sg * 16 + 4];                 \
    const float4 wv2 = *(const float4*)&wLds[t][sg * 16 + 8];                 \
    const v2f w6 = *(const v2f*)&wLds[t][sg * 16 + 12];                       \
    const v2f w[7] = {{wv0.x, wv0.y}, {wv0.z, wv0.w}, {wv1.x, wv1.y},         \
                      {wv1.z, wv1.w}, {wv2.x, wv2.y}, {wv2.z, wv2.w}, w6};

__global__ __launch_bounds__(256) void k2a_maps(
    const int* __restrict__ cseq, const int* __restrict__ corr,
    const int* __restrict__ ncp,
    const float* __restrict__ wTab, const float* __restrict__ eaTab,
    float* __restrict__ Aout, float* __restrict__ Bout)
{
    __shared__ int cL[LL], xL[LL];
    __shared__ float __align__(16) wLds[LL][64];
    __shared__ float2 __align__(8) eaLds[LL][64];

    SCAN_STAGE()
    __syncthreads();

    v2f A[7], Bc[7];
    #pragma unroll
    for (int j = 0; j < 7; ++j) { A[j] = (v2f){1.f, 1.f}; Bc[j] = (v2f){0.f, 0.f}; }

    const v2f one2 = {1.f, 1.f};
    #pragma unroll 2
    for (int t = 0; t < LL; ++t) {
        LOADW(t)
        const float2 ea = eaLds[t][lane];
        const v2f e2 = {ea.x, ea.x}, a2 = {ea.y, ea.y};
        #pragma unroll
        for (int j = 0; j < 7; ++j) {
            const v2f al = __builtin_elementwise_fma(-w[j], e2, one2); // 1-w*e
            const v2f be = w[j] * a2;                                  // w*a
            A[j]  = al * A[j];
            Bc[j] = __builtin_elementwise_fma(al, Bc[j], be);          // al*B+be
        }
    }

    const int st = (SS * sg) >> 2, en = (SS * (sg + 1)) >> 2;
    float* Ap = Aout + (size_t)blockIdx.x * SS * DD;
    float* Bp = Bout + (size_t)blockIdx.x * SS * DD;
    #pragma unroll
    for (int j = 0; j < 6; ++j) {
        const int s0 = st + 2 * j;
        Ap[(size_t)s0 * DD + lane] = A[j].x;
        Ap[(size_t)(s0 + 1) * DD + lane] = A[j].y;
        Bp[(size_t)s0 * DD + lane] = Bc[j].x;
        Bp[(size_t)(s0 + 1) * DD + lane] = Bc[j].y;
    }
    if (st + 12 < en) {
        Ap[(size_t)(st + 12) * DD + lane] = A[6].x;
        Bp[(size_t)(st + 12) * DD + lane] = Bc[6].x;
    }
}

// ---------------------------------------------------------------------------
// Fused: prefix-combine + replay + output head. LDS union (60KB):
//   scan phase:  wLds[50][64] | eaLds[50][64](f2) | parts[10][4][64] | rL
//   head phase:  wfS[128][64] | kS[50][64]                          | rL
// ---------------------------------------------------------------------------
__global__ __launch_bounds__(256) void k2_fused(
    const int* __restrict__ cseq, const int* __restrict__ corr,
    const int* __restrict__ ncp,
    const float* __restrict__ wTab, const float* __restrict__ eaTab,
    const float* __restrict__ Mv0,
    const float* __restrict__ Abuf, const float* __restrict__ Bbuf,
    const float* __restrict__ embed_key,
    const float* __restrict__ Wf, const float* __restrict__ bf,
    const float* __restrict__ Wab, const float* __restrict__ bab,
    const float* __restrict__ Wd, const float* __restrict__ bd,
    float* __restrict__ out)
{
    __shared__ int cL[LL], xL[LL];
    __shared__ __align__(16) char smemRaw[61440];
    float  (*wLds)[64]     = (float (*)[64])(smemRaw);             // 12800B
    float2 (*eaLds)[64]    = (float2 (*)[64])(smemRaw + 12800);    // 25600B
    float  (*parts)[4][64] = (float (*)[4][64])(smemRaw + 38400);  // 10240B
    float  (*rL)[64]       = (float (*)[64])(smemRaw + 48640);     // 12800B
    // head-phase aliases (scan-phase regions dead by then):
    float  (*wfS)[64]      = (float (*)[64])(smemRaw);             // 32768B
    float  (*kS)[64]       = (float (*)[64])(smemRaw + 32768);     // 12800B

    SCAN_STAGE()

    // ---- prefix-compose start state (k2b folded in): m = (prefix maps)(Mv0)
    const int st = (SS * sg) >> 2, en = (SS * (sg + 1)) >> 2;
    v2f m[7];
    #pragma unroll
    for (int j = 0; j < 7; ++j) {
        const int s0 = st + 2 * j, s1 = s0 + 1;
        v2f mm = {0.f, 0.f};
        if (s0 < en) mm.x = Mv0[(size_t)s0 * DD + lane];
        if (s1 < en) mm.y = Mv0[(size_t)s1 * DD + lane];
        m[j] = mm;
    }
    for (int q = 0; q < p; ++q) {
        const float* Aq = Abuf + (size_t)(b * PP + q) * SS * DD;
        const float* Bq = Bbuf + (size_t)(b * PP + q) * SS * DD;
        #pragma unroll
        for (int j = 0; j < 7; ++j) {
            const int s0 = st + 2 * j, s1 = s0 + 1;
            if (s0 < en)
                m[j].x = fmaf(Aq[(size_t)s0 * DD + lane], m[j].x,
                              Bq[(size_t)s0 * DD + lane]);
            if (s1 < en)
                m[j].y = fmaf(Aq[(size_t)s1 * DD + lane], m[j].y,
                              Bq[(size_t)s1 * DD + lane]);
        }
    }
    __syncthreads();   // wLds/eaLds staged

    // ---- replay 50 steps, r -> rL (LDS)
    for (int tq = 0; tq < LL / 10; ++tq) {
        #pragma unroll
        for (int u = 0; u < 10; ++u) {
            const int t = tq * 10 + u;
            LOADW(t)
            const float2 ea = eaLds[t][lane];
            const v2f e2 = {ea.x, ea.x}, na2 = {-ea.y, -ea.y};
            v2f r2 = {0.f, 0.f};
            #pragma unroll
            for (int j = 0; j < 7; ++j) {
                const v2f mv = m[j];
                r2 = __builtin_elementwise_fma(w[j], mv, r2);
                const v2f g = __builtin_elementwise_fma(e2, mv, na2); // e*m-a
                m[j] = __builtin_elementwise_fma(-w[j], g, mv);       // m-w*g
            }
            parts[u][sg][lane] = r2.x + r2.y;
        }
        __syncthreads();
        for (int o = tid; o < 10 * DD; o += 256) {
            const int u2 = o >> 6, d2 = o & 63;
            rL[tq * 10 + u2][d2] = parts[u2][0][d2] + parts[u2][1][d2]
                                 + parts[u2][2][d2] + parts[u2][3][d2];
        }
        __syncthreads();
    }

    // ---- head phase (k3 folded in): overwrite dead scan LDS with Wf, k
    #pragma unroll
    for (int k8 = 0; k8 < 8; ++k8) {
        const int idx = tid + k8 * 256;           // < 2048 float4
        ((float4*)wfS)[idx] = ((const float4*)Wf)[idx];
    }
    for (int i = tid; i < LL * 64; i += 256) {
        const int t = i >> 6, d = i & 63;
        kS[t][d] = embed_key[cL[t] * DD + d];
    }
    __syncthreads();

    const int j = lane;
    const float bf_j = bf[j];
    const float wab_j = Wab[j];
    const float wd_j = Wd[j];
    const float bab0 = bab[0], bd0 = bd[0];
    float* ob = out + (size_t)b * TT + t0g;

    for (int g8 = 0; g8 < 13; ++g8) {
        const int t = g8 * 4 + sg;               // 4 t's per pass, wave = one t
        if (t < LL) {
            float acc = bf_j;
            #pragma unroll
            for (int i = 0; i < DD; ++i)
                acc = fmaf(rL[t][i], wfS[i][j], acc);
            #pragma unroll
            for (int i = 0; i < DD; ++i)
                acc = fmaf(kS[t][i], wfS[DD + i][j], acc);
            const float f = tanhf(acc);
            float pv = f * wab_j;
            float qv = kS[t][j] * wd_j;
            #pragma unroll
            for (int off = 32; off >= 1; off >>= 1) {
                pv += __shfl_xor(pv, off);
                qv += __shfl_xor(qv, off);
            }
            if (j == 0) {
                const float stu  = tanhf(pv + bab0);
                const float diff = tanhf(qv + bd0);
                ob[t] = sigmoidf_(3.0f * stu - diff);
            }
        }
    }
}

// ---------------------------------------------------------------------------
extern "C" void kernel_launch(void* const* d_in, const int* in_sizes, int n_in,
                              void* d_out, int out_size, void* d_ws, size_t ws_size,
                              hipStream_t stream)
{
    const int*   concept_seq = (const int*)  d_in[0];
    const int*   correct_seq = (const int*)  d_in[1];
    const int*   num_concept = (const int*)  d_in[2];
    const float* embed_key   = (const float*)d_in[3];
    const float* embed_value = (const float*)d_in[4];
    const float* Mk          = (const float*)d_in[5];
    const float* Mv0         = (const float*)d_in[6];
    const float* Wf          = (const float*)d_in[7];
    const float* bf          = (const float*)d_in[8];
    const float* We          = (const float*)d_in[9];
    const float* be          = (const float*)d_in[10];
    const float* Wa          = (const float*)d_in[11];
    const float* ba          = (const float*)d_in[12];
    const float* Wab         = (const float*)d_in[13];
    const float* bab         = (const float*)d_in[14];
    const float* Wd          = (const float*)d_in[15];
    const float* bd          = (const float*)d_in[16];
    float* out = (float*)d_out;

    const int NCON = in_sizes[3] / DD;   // 1024
    const int NV   = in_sizes[4] / DD;   // 2048

    float* wTab  = (float*)d_ws;                         // NCON*SS
    float* eaTab = wTab + (size_t)NCON * SS;             // NV*DD*2
    float* Abuf  = eaTab + (size_t)NV * DD * 2;          // BB*PP*SS*DD
    float* Bbuf  = Abuf + (size_t)BB * PP * SS * DD;     // BB*PP*SS*DD

    k1_tables<<<NCON + NV, 64, 0, stream>>>(
        embed_key, embed_value, Mk, We, be, Wa, ba,
        NCON, NV, wTab, eaTab);

    k2a_maps<<<BB * PP, 256, 0, stream>>>(
        concept_seq, correct_seq, num_concept,
        wTab, eaTab, Abuf, Bbuf);

    k2_fused<<<BB * PP, 256, 0, stream>>>(
        concept_seq, correct_seq, num_concept,
        wTab, eaTab, Mv0, Abuf, Bbuf,
        embed_key, Wf, bf, Wab, bab, Wd, bd, out);
}

// Round 14
// 201.907 us; speedup vs baseline: 1.1138x; 1.1138x over previous
//
#include <hip/hip_runtime.h>
#include <hip/hip_bf16.h>
#include <math.h>

#define BB 64
#define TT 500
#define DD 64
#define SS 50
#define PP 10            // chunks
#define LL 50            // steps per chunk (PP*LL == TT)

typedef float v2f __attribute__((ext_vector_type(2)));

__device__ __forceinline__ float sigmoidf_(float x) { return 1.0f / (1.0f + __expf(-x)); }

// ---------------------------------------------------------------------------
// Kernel 1: tables. blocks [0,ncon): wTab[c][50] = softmax(embed_key[c]·Mk^T)
//   blocks [ncon,ncon+nv): eaTab[x][d] = {sigmoid(ev@We+be), tanh(ev@Wa+ba)}
// ---------------------------------------------------------------------------
__global__ __launch_bounds__(64) void k1_tables(
    const float* __restrict__ embed_key,
    const float* __restrict__ embed_value,
    const float* __restrict__ Mk,
    const float* __restrict__ We, const float* __restrict__ be,
    const float* __restrict__ Wa, const float* __restrict__ ba,
    int ncon, int nv,
    float* __restrict__ wTab, float* __restrict__ eaTab)
{
    const int lane = threadIdx.x;
    if ((int)blockIdx.x < ncon) {
        const int c = blockIdx.x;
        __shared__ float mkS[SS][DD + 1];
        __shared__ float kS[DD];
        kS[lane] = embed_key[c * DD + lane];
        for (int s = 0; s < SS; ++s)
            mkS[s][lane] = Mk[s * DD + lane];
        __syncthreads();

        float sc = -1e30f;
        if (lane < SS) {
            float acc = 0.f;
            #pragma unroll
            for (int dd = 0; dd < DD; ++dd)
                acc = fmaf(kS[dd], mkS[lane][dd], acc);
            sc = acc;
        }
        float m = sc;
        #pragma unroll
        for (int off = 32; off >= 1; off >>= 1)
            m = fmaxf(m, __shfl_xor(m, off));
        float ex = (lane < SS) ? __expf(sc - m) : 0.f;
        float ssum = ex;
        #pragma unroll
        for (int off = 32; off >= 1; off >>= 1)
            ssum += __shfl_xor(ssum, off);
        if (lane < SS)
            wTab[c * SS + lane] = ex / ssum;
    } else {
        const int x = blockIdx.x - ncon;
        __shared__ float vS[DD];
        vS[lane] = embed_value[x * DD + lane];
        __syncthreads();
        float acc_e = be[lane];
        float acc_a = ba[lane];
        #pragma unroll
        for (int i = 0; i < DD; ++i) {
            const float vi = vS[i];
            acc_e = fmaf(vi, We[i * DD + lane], acc_e);
            acc_a = fmaf(vi, Wa[i * DD + lane], acc_a);
        }
        float2 ea;
        ea.x = sigmoidf_(acc_e);
        ea.y = tanhf(acc_a);
        *(float2*)&eaTab[((size_t)x * DD + lane) * 2] = ea;
    }
}

// ---------------------------------------------------------------------------
// PARALLEL SCAN over t. Recurrence per (b,s,d): m <- al*m + be,
// al = 1-w*e, be = w*a. Chunk maps compose associatively.
//   k2a:     per (b,p) compose the 50-step chunk map (A,B)
//   k2fused: prefix-compose start state in regs, replay 50 steps into
//            rLT (transposed LDS), then TILED head (r12-k3 structure:
//            4x4 register tiles, float4 LDS reads -- NOT the r13 serial
//            dot whose 128-deep acc chain + 3300 scalar ds_reads/wave
//            cost 120us).
// ---------------------------------------------------------------------------

#define SCAN_STAGE()                                                          \
    const int b = blockIdx.x / PP, p = blockIdx.x % PP;                       \
    const int tid = threadIdx.x;                                              \
    const int lane = tid & 63, sg = tid >> 6;                                 \
    const int t0g = p * LL;                                                   \
    if (tid < LL) {                                                           \
        const int c = cseq[b * TT + t0g + tid];                               \
        cL[tid] = c;                                                          \
        xL[tid] = c + ncp[0] * corr[b * TT + t0g + tid];                      \
    }                                                                         \
    __syncthreads();                                                          \
    for (int i = tid; i < LL * 64; i += 256) {                                \
        const int t = i >> 6, l = i & 63;                                     \
        const int sg_ = l >> 4, j_ = l & 15;                                  \
        const int st_ = (SS * sg_) >> 2, en_ = (SS * (sg_ + 1)) >> 2;         \
        const int s_ = st_ + j_;                                              \
        wLds[t][l] = (s_ < en_) ? wTab[cL[t] * SS + s_] : 0.f;                \
        eaLds[t][l] = *(const float2*)&eaTab[((size_t)xL[t] * DD + l) * 2];   \
    }

#define LOADW(t)                                                              \
    const float4 wv0 = *(const float4*)&wLds[t][sg * 16];                     \
    const float4 wv1 = *(const float4*)&wLds[t][sg * 16 + 4];                 \
    const float4 wv2 = *(const float4*)&wLds[t][sg * 16 + 8];                 \
    const v2f w6 = *(const v2f*)&wLds[t][sg * 16 + 12];                       \
    const v2f w[7] = {{wv0.x, wv0.y}, {wv0.z, wv0.w}, {wv1.x, wv1.y},         \
                      {wv1.z, wv1.w}, {wv2.x, wv2.y}, {wv2.z, wv2.w}, w6};

__global__ __launch_bounds__(256) void k2a_maps(
    const int* __restrict__ cseq, const int* __restrict__ corr,
    const int* __restrict__ ncp,
    const float* __restrict__ wTab, const float* __restrict__ eaTab,
    float* __restrict__ Aout, float* __restrict__ Bout)
{
    __shared__ int cL[LL], xL[LL];
    __shared__ float __align__(16) wLds[LL][64];
    __shared__ float2 __align__(8) eaLds[LL][64];

    SCAN_STAGE()
    __syncthreads();

    v2f A[7], Bc[7];
    #pragma unroll
    for (int j = 0; j < 7; ++j) { A[j] = (v2f){1.f, 1.f}; Bc[j] = (v2f){0.f, 0.f}; }

    const v2f one2 = {1.f, 1.f};
    #pragma unroll 2
    for (int t = 0; t < LL; ++t) {
        LOADW(t)
        const float2 ea = eaLds[t][lane];
        const v2f e2 = {ea.x, ea.x}, a2 = {ea.y, ea.y};
        #pragma unroll
        for (int j = 0; j < 7; ++j) {
            const v2f al = __builtin_elementwise_fma(-w[j], e2, one2); // 1-w*e
            const v2f be = w[j] * a2;                                  // w*a
            A[j]  = al * A[j];
            Bc[j] = __builtin_elementwise_fma(al, Bc[j], be);          // al*B+be
        }
    }

    const int st = (SS * sg) >> 2, en = (SS * (sg + 1)) >> 2;
    float* Ap = Aout + (size_t)blockIdx.x * SS * DD;
    float* Bp = Bout + (size_t)blockIdx.x * SS * DD;
    #pragma unroll
    for (int j = 0; j < 6; ++j) {
        const int s0 = st + 2 * j;
        Ap[(size_t)s0 * DD + lane] = A[j].x;
        Ap[(size_t)(s0 + 1) * DD + lane] = A[j].y;
        Bp[(size_t)s0 * DD + lane] = Bc[j].x;
        Bp[(size_t)(s0 + 1) * DD + lane] = Bc[j].y;
    }
    if (st + 12 < en) {
        Ap[(size_t)(st + 12) * DD + lane] = A[6].x;
        Bp[(size_t)(st + 12) * DD + lane] = Bc[6].x;
    }
}

// ---------------------------------------------------------------------------
// Fused: prefix-combine + replay + TILED output head. LDS (61.95KB):
//   scan phase:  [A] wLds(12.8K) | eaLds(25.6K) | parts(10.2K)   [B] rLT(13.3K)
//   head phase:  [A] wfS(32K) | kST(13.3K)                       [B] rLT(13.3K)
// rLT/kST are [64][52] transposed (t in cols, 52-pad: rows 16B-aligned).
// ---------------------------------------------------------------------------
__global__ __launch_bounds__(256) void k2_fused(
    const int* __restrict__ cseq, const int* __restrict__ corr,
    const int* __restrict__ ncp,
    const float* __restrict__ wTab, const float* __restrict__ eaTab,
    const float* __restrict__ Mv0,
    const float* __restrict__ Abuf, const float* __restrict__ Bbuf,
    const float* __restrict__ embed_key,
    const float* __restrict__ Wf, const float* __restrict__ bf,
    const float* __restrict__ Wab, const float* __restrict__ bab,
    const float* __restrict__ Wd, const float* __restrict__ bd,
    float* __restrict__ out)
{
    __shared__ int cL[LL], xL[LL];
    __shared__ __align__(16) char smemRaw[61952];
    float  (*wLds)[64]     = (float (*)[64])(smemRaw);             // 12800B
    float2 (*eaLds)[64]    = (float2 (*)[64])(smemRaw + 12800);    // 25600B
    float  (*parts)[4][64] = (float (*)[4][64])(smemRaw + 38400);  // 10240B
    float  (*rLT)[52]      = (float (*)[52])(smemRaw + 48640);     // 13312B persists
    // head-phase aliases (scan regions dead by then):
    float  (*wfS)[64]      = (float (*)[64])(smemRaw);             // 32768B
    float  (*kST)[52]      = (float (*)[52])(smemRaw + 32768);     // 13312B

    SCAN_STAGE()

    // ---- prefix-compose start state: m = (prefix chunk maps)(Mv0)
    const int st = (SS * sg) >> 2, en = (SS * (sg + 1)) >> 2;
    v2f m[7];
    #pragma unroll
    for (int j = 0; j < 7; ++j) {
        const int s0 = st + 2 * j, s1 = s0 + 1;
        v2f mm = {0.f, 0.f};
        if (s0 < en) mm.x = Mv0[(size_t)s0 * DD + lane];
        if (s1 < en) mm.y = Mv0[(size_t)s1 * DD + lane];
        m[j] = mm;
    }
    for (int q = 0; q < p; ++q) {
        const float* Aq = Abuf + (size_t)(b * PP + q) * SS * DD;
        const float* Bq = Bbuf + (size_t)(b * PP + q) * SS * DD;
        #pragma unroll
        for (int j = 0; j < 7; ++j) {
            const int s0 = st + 2 * j, s1 = s0 + 1;
            if (s0 < en)
                m[j].x = fmaf(Aq[(size_t)s0 * DD + lane], m[j].x,
                              Bq[(size_t)s0 * DD + lane]);
            if (s1 < en)
                m[j].y = fmaf(Aq[(size_t)s1 * DD + lane], m[j].y,
                              Bq[(size_t)s1 * DD + lane]);
        }
    }
    __syncthreads();   // wLds/eaLds staged

    // ---- replay 50 steps; r -> rLT (transposed: rLT[d][t])
    for (int tq = 0; tq < LL / 10; ++tq) {
        #pragma unroll
        for (int u = 0; u < 10; ++u) {
            const int t = tq * 10 + u;
            LOADW(t)
            const float2 ea = eaLds[t][lane];
            const v2f e2 = {ea.x, ea.x}, na2 = {-ea.y, -ea.y};
            v2f r2 = {0.f, 0.f};
            #pragma unroll
            for (int j = 0; j < 7; ++j) {
                const v2f mv = m[j];
                r2 = __builtin_elementwise_fma(w[j], mv, r2);
                const v2f g = __builtin_elementwise_fma(e2, mv, na2); // e*m-a
                m[j] = __builtin_elementwise_fma(-w[j], g, mv);       // m-w*g
            }
            parts[u][sg][lane] = r2.x + r2.y;
        }
        __syncthreads();
        for (int o = tid; o < 10 * DD; o += 256) {
            const int u2 = o >> 6, d2 = o & 63;
            rLT[d2][tq * 10 + u2] = parts[u2][0][d2] + parts[u2][1][d2]
                                  + parts[u2][2][d2] + parts[u2][3][d2];
        }
        __syncthreads();   // wLds/eaLds now dead; rLT chunk complete
    }

    // ---- head staging over dead scan LDS: Wf and k (transposed)
    #pragma unroll
    for (int k8 = 0; k8 < 8; ++k8) {
        const int idx = tid + k8 * 256;           // 2048 float4 = 32KB
        ((float4*)wfS)[idx] = ((const float4*)Wf)[idx];
    }
    for (int i = tid; i < LL * 64; i += 256) {
        const int t = i >> 6, d = i & 63;
        kST[d][t] = embed_key[cL[t] * DD + d];
    }
    __syncthreads();

    // ---- tiled head: thread (tx,ty) owns 4t x 4j; ty<13 covers t<52
    const int tx = tid & 15, ty = tid >> 4;
    float acc[4][4] = {{0.f}};
    if (ty < 13) {
        #pragma unroll 8
        for (int i = 0; i < 64; ++i) {          // r part
            const float4 wf = *(const float4*)&wfS[i][tx * 4];
            const float4 ct = *(const float4*)&rLT[i][ty * 4];
            acc[0][0] = fmaf(ct.x, wf.x, acc[0][0]);
            acc[0][1] = fmaf(ct.x, wf.y, acc[0][1]);
            acc[0][2] = fmaf(ct.x, wf.z, acc[0][2]);
            acc[0][3] = fmaf(ct.x, wf.w, acc[0][3]);
            acc[1][0] = fmaf(ct.y, wf.x, acc[1][0]);
            acc[1][1] = fmaf(ct.y, wf.y, acc[1][1]);
            acc[1][2] = fmaf(ct.y, wf.z, acc[1][2]);
            acc[1][3] = fmaf(ct.y, wf.w, acc[1][3]);
            acc[2][0] = fmaf(ct.z, wf.x, acc[2][0]);
            acc[2][1] = fmaf(ct.z, wf.y, acc[2][1]);
            acc[2][2] = fmaf(ct.z, wf.z, acc[2][2]);
            acc[2][3] = fmaf(ct.z, wf.w, acc[2][3]);
            acc[3][0] = fmaf(ct.w, wf.x, acc[3][0]);
            acc[3][1] = fmaf(ct.w, wf.y, acc[3][1]);
            acc[3][2] = fmaf(ct.w, wf.z, acc[3][2]);
            acc[3][3] = fmaf(ct.w, wf.w, acc[3][3]);
        }
        #pragma unroll 8
        for (int i = 0; i < 64; ++i) {          // k part
            const float4 wf = *(const float4*)&wfS[64 + i][tx * 4];
            const float4 ct = *(const float4*)&kST[i][ty * 4];
            acc[0][0] = fmaf(ct.x, wf.x, acc[0][0]);
            acc[0][1] = fmaf(ct.x, wf.y, acc[0][1]);
            acc[0][2] = fmaf(ct.x, wf.z, acc[0][2]);
            acc[0][3] = fmaf(ct.x, wf.w, acc[0][3]);
            acc[1][0] = fmaf(ct.y, wf.x, acc[1][0]);
            acc[1][1] = fmaf(ct.y, wf.y, acc[1][1]);
            acc[1][2] = fmaf(ct.y, wf.z, acc[1][2]);
            acc[1][3] = fmaf(ct.y, wf.w, acc[1][3]);
            acc[2][0] = fmaf(ct.z, wf.x, acc[2][0]);
            acc[2][1] = fmaf(ct.z, wf.y, acc[2][1]);
            acc[2][2] = fmaf(ct.z, wf.z, acc[2][2]);
            acc[2][3] = fmaf(ct.z, wf.w, acc[2][3]);
            acc[3][0] = fmaf(ct.w, wf.x, acc[3][0]);
            acc[3][1] = fmaf(ct.w, wf.y, acc[3][1]);
            acc[3][2] = fmaf(ct.w, wf.z, acc[3][2]);
            acc[3][3] = fmaf(ct.w, wf.w, acc[3][3]);
        }
    }

    // ---- epilogue: tanh + Wab/Wd dots, shfl-reduce over the 16-lane tx group
    if (ty < 13) {
        const float4 bf4  = *(const float4*)&bf[tx * 4];
        const float4 wab4 = *(const float4*)&Wab[tx * 4];
        const float4 wd4  = *(const float4*)&Wd[tx * 4];
        const float bab0 = bab[0], bd0 = bd[0];
        float* ob = out + (size_t)b * TT + t0g;
        #pragma unroll
        for (int ii = 0; ii < 4; ++ii) {
            const int t = ty * 4 + ii;
            float pv = tanhf(acc[ii][0] + bf4.x) * wab4.x
                     + tanhf(acc[ii][1] + bf4.y) * wab4.y
                     + tanhf(acc[ii][2] + bf4.z) * wab4.z
                     + tanhf(acc[ii][3] + bf4.w) * wab4.w;
            float qv = kST[tx * 4 + 0][t] * wd4.x
                     + kST[tx * 4 + 1][t] * wd4.y
                     + kST[tx * 4 + 2][t] * wd4.z
                     + kST[tx * 4 + 3][t] * wd4.w;
            #pragma unroll
            for (int off = 8; off >= 1; off >>= 1) {
                pv += __shfl_xor(pv, off);
                qv += __shfl_xor(qv, off);
            }
            if (tx == 0 && t < LL) {
                const float stu  = tanhf(pv + bab0);
                const float diff = tanhf(qv + bd0);
                ob[t] = sigmoidf_(3.0f * stu - diff);
            }
        }
    }
}

// ---------------------------------------------------------------------------
extern "C" void kernel_launch(void* const* d_in, const int* in_sizes, int n_in,
                              void* d_out, int out_size, void* d_ws, size_t ws_size,
                              hipStream_t stream)
{
    const int*   concept_seq = (const int*)  d_in[0];
    const int*   correct_seq = (const int*)  d_in[1];
    const int*   num_concept = (const int*)  d_in[2];
    const float* embed_key   = (const float*)d_in[3];
    const float* embed_value = (const float*)d_in[4];
    const float* Mk          = (const float*)d_in[5];
    const float* Mv0         = (const float*)d_in[6];
    const float* Wf          = (const float*)d_in[7];
    const float* bf          = (const float*)d_in[8];
    const float* We          = (const float*)d_in[9];
    const float* be          = (const float*)d_in[10];
    const float* Wa          = (const float*)d_in[11];
    const float* ba          = (const float*)d_in[12];
    const float* Wab         = (const float*)d_in[13];
    const float* bab         = (const float*)d_in[14];
    const float* Wd          = (const float*)d_in[15];
    const float* bd          = (const float*)d_in[16];
    float* out = (float*)d_out;

    const int NCON = in_sizes[3] / DD;   // 1024
    const int NV   = in_sizes[4] / DD;   // 2048

    float* wTab  = (float*)d_ws;                         // NCON*SS
    float* eaTab = wTab + (size_t)NCON * SS;             // NV*DD*2
    float* Abuf  = eaTab + (size_t)NV * DD * 2;          // BB*PP*SS*DD
    float* Bbuf  = Abuf + (size_t)BB * PP * SS * DD;     // BB*PP*SS*DD

    k1_tables<<<NCON + NV, 64, 0, stream>>>(
        embed_key, embed_value, Mk, We, be, Wa, ba,
        NCON, NV, wTab, eaTab);

    k2a_maps<<<BB * PP, 256, 0, stream>>>(
        concept_seq, correct_seq, num_concept,
        wTab, eaTab, Abuf, Bbuf);

    k2_fused<<<BB * PP, 256, 0, stream>>>(
        concept_seq, correct_seq, num_concept,
        wTab, eaTab, Mv0, Abuf, Bbuf,
        embed_key, Wf, bf, Wab, bab, Wd, bd, out);
}